// Round 9
// baseline (219.582 us; speedup 1.0000x reference)
//
#include <hip/hip_runtime.h>

// Fused: per-channel affine+relu -> dilated(2) 3x3 box-sum (zero pad) ->
// sigmoid gate -> multiply -> 2x nearest upsample -> add y.
//
// R0-R12 ledger: nine structurally distinct kernels (reg loads, LDS-staged,
// DMA-staged, pinned, unrolled) all land 63-68 us; FETCH/WRITE identical.
// Refuted: serialized-latency COUNT (R11), batching (R7/R9), in-flight
// bytes (R12). The one invariant left vs m13's 6.3 TB/s float4-copy
// reference: ONE-SHOT WAVES. Every variant pays a full pipeline
// fill/drain/teardown per ~26-instruction wave life; the 6.3 TB/s copy is a
// persistent grid-stride streamer that re-issues continuously.
//
// R13: persistent-block double-buffered DMA pipeline (the Sec-5 GEMM staging
// pattern): 1536 blocks (6/CU exact), 8 rows each (512%8==0 -> blocks never
// cross images). Per iteration k: y rows for k+1 are DMA-staged via
// global_load_lds (register-free -> un-serializable by the allocator) into
// buf[(k+1)&1] while iter k computes from buf[k&1]. __syncthreads at the
// top of each iteration drains DMA(k) issued a FULL COMPUTE PHASE earlier
// -> latency hidden. x taps: 9 float2 register loads (L2/L3-warm under the
// XCD swizzle, kept). Stores fire-and-forget.
// Race check: DMA(k+1) targets the buffer last READ in iter k-1; the
// barrier at top of iter k guarantees all waves finished those reads.

#define DIA 2

typedef __attribute__((address_space(3))) void lds_void;
typedef const __attribute__((address_space(1))) void gmem_void;

__global__ __launch_bounds__(256) void fused_kernel(
    const float* __restrict__ x, const float* __restrict__ y,
    const float* __restrict__ w1v, const float* __restrict__ b1v,
    const float* __restrict__ w2v, const float* __restrict__ b2v,
    float* __restrict__ out)
{
    constexpr int C = 3, H = 512, W = 512, W2 = 1024;
    constexpr int ROWS = 8;                    // rows per block
    constexpr int BPI  = H / ROWS;             // 64 blocks per image
    constexpr int NBLK = 24 * BPI;             // 1536 (= 6 per CU exactly)
    constexpr int CHUNK = NBLK / 8;            // 192 blocks = 3 images / XCD

    __shared__ float ys[2][2 * W2];            // 2 bufs x 2 y-rows = 16 KB

    // XCD-aware swizzle (1536 % 8 == 0 -> bijective).
    int g = blockIdx.x;
    int l = (g & 7) * CHUNK + (g >> 3);

    int bc  = l / BPI;                         // 0..23, scalar per block
    int h0  = (l % BPI) * ROWS;                // first of 8 rows, same image
    int c   = bc % C;
    int tid = (int)threadIdx.x;
    int w0  = tid * 2;                         // even, 0..510
    int lane = tid & 63;
    int wv  = __builtin_amdgcn_readfirstlane(tid >> 6);  // wave 0..3

    const float s_w1 = w1v[c], s_b1 = b1v[c];
    const float s_w2 = w2v[c], s_b2 = b2v[c];

    const float* __restrict__ ximg = x + (size_t)bc * H * W;
    const size_t ybase = (size_t)bc * (2 * H) * W2;

    const bool lok = (w0 > 0), rok = (w0 + 2 < W);
    const float mL = lok ? 1.f : 0.f;
    const float mR = rok ? 1.f : 0.f;
    const int wl = lok ? (w0 - 2) : w0;        // even -> 8B-aligned
    const int wr = rok ? (w0 + 2) : w0;

    // DMA-stage both y rows of logical row (h0+k) into buffer buf.
    // Each call: wave-uniform LDS base, HW adds lane*16; 4 waves x 1 KB
    // cover each 4 KB row. Source addresses always in-bounds.
    auto stage = [&](int k, int buf) {
        size_t yr = ybase + (size_t)(2 * (h0 + k)) * W2;
        const float* gpa = y + yr +      wv * 256 + lane * 4;
        const float* gpb = y + yr + W2 + wv * 256 + lane * 4;
        __builtin_amdgcn_global_load_lds((gmem_void*)gpa,
                                         (lds_void*)(&ys[buf][wv * 256]), 16, 0, 0);
        __builtin_amdgcn_global_load_lds((gmem_void*)gpb,
                                         (lds_void*)(&ys[buf][W2 + wv * 256]), 16, 0, 0);
    };

    auto act = [&](float v) { return fmaxf(fmaf(v, s_w1, s_b1), 0.f); };

    stage(0, 0);                               // prologue prefetch

    for (int k = 0; k < ROWS; ++k) {
        // Drains DMA(k) (issued one full compute phase ago) + old stores,
        // and fences buf[(k+1)&1] reads from iter k-1 before re-staging it.
        __syncthreads();

        const int h = h0 + k;
        const float* xrow = ximg + (size_t)h * W;
        const bool ok0 = (h >= DIA), ok2 = (h < H - DIA);
        const float m0 = ok0 ? 1.f : 0.f;
        const float m2 = ok2 ? 1.f : 0.f;
        const float* r0 = ok0 ? (xrow - DIA * W) : xrow;   // clamped
        const float* r2 = ok2 ? (xrow + DIA * W) : xrow;

        // x taps: register loads, L2/L3-warm (issued before the DMA calls so
        // the compiler's auto-waitcnt for them never drains the prefetch).
        float2 L0 = *(const float2*)(r0 + wl);
        float2 M0 = *(const float2*)(r0 + w0);
        float2 R0 = *(const float2*)(r0 + wr);
        float2 L1 = *(const float2*)(xrow + wl);
        float2 M1 = *(const float2*)(xrow + w0);
        float2 R1 = *(const float2*)(xrow + wr);
        float2 L2 = *(const float2*)(r2 + wl);
        float2 M2 = *(const float2*)(r2 + w0);
        float2 R2 = *(const float2*)(r2 + wr);

        // Prefetch next iteration's y rows into the alternate buffer.
        if (k + 1 < ROWS) stage(k + 1, (k + 1) & 1);

        // Current y rows from LDS (contiguous b128 per lane).
        float4 ya = *(const float4*)&ys[k & 1][2 * w0];
        float4 yb = *(const float4*)&ys[k & 1][W2 + 2 * w0];

        // ---- compute ----
        float xo0 = act(M1.x);
        float xo1 = act(M1.y);

        float sum0 = mL * act(L1.x) + xo0 + mR * act(R1.x);
        float sum1 = mL * act(L1.y) + xo1 + mR * act(R1.y);
        sum0 += m0 * (mL * act(L0.x) + act(M0.x) + mR * act(R0.x));
        sum1 += m0 * (mL * act(L0.y) + act(M0.y) + mR * act(R0.y));
        sum0 += m2 * (mL * act(L2.x) + act(M2.x) + mR * act(R2.x));
        sum1 += m2 * (mL * act(L2.y) + act(M2.y) + mR * act(R2.y));

        float z0 = fmaf(sum0, s_w2, s_b2);
        float z1 = fmaf(sum1, s_w2, s_b2);
        float o0 = xo0 / (1.f + __expf(-z0));
        float o1 = xo1 / (1.f + __expf(-z1));

        // ---- 2x nearest upsample + add y (lane-contiguous float4) ----
        size_t obase = ybase + (size_t)(2 * h) * W2 + (size_t)(2 * w0);
        *(float4*)(out + obase)      = make_float4(ya.x + o0, ya.y + o0, ya.z + o1, ya.w + o1);
        *(float4*)(out + obase + W2) = make_float4(yb.x + o0, yb.y + o0, yb.z + o1, yb.w + o1);
    }
}

extern "C" void kernel_launch(void* const* d_in, const int* in_sizes, int n_in,
                              void* d_out, int out_size, void* d_ws, size_t ws_size,
                              hipStream_t stream) {
    const float* x  = (const float*)d_in[0];
    const float* y  = (const float*)d_in[1];
    const float* w1 = (const float*)d_in[2];
    const float* b1 = (const float*)d_in[3];
    const float* w2 = (const float*)d_in[4];
    const float* b2 = (const float*)d_in[5];
    float* out = (float*)d_out;

    int grid = 1536, block = 256;    // 6 blocks/CU exact, 8 rows per block
    fused_kernel<<<grid, block, 0, stream>>>(x, y, w1, b1, w2, b2, out);
}

// Round 10
// 208.193 us; speedup vs baseline: 1.0547x; 1.0547x over previous
//
#include <hip/hip_runtime.h>

// Fused: per-channel affine+relu -> dilated(2) 3x3 box-sum (zero pad) ->
// sigmoid gate -> multiply -> 2x nearest upsample -> add y.
//
// R0-R13 ledger: ten structural variants (reg/LDS/DMA loads, pins, pipelines,
// persistent+barriers, swizzle on/off) all land 63-78 us; best is the SIMPLE
// one-shot kernel (63.2). FETCH (61-86 MB) < 126 MB compulsory reads -> x,y
// are L3-resident; effective service rate pinned at ~3.5 TB/s regardless of
// structure. Refuted: latency-count, batching, in-flight-bytes, traffic-
// reduction theories.
//
// R14: the last untried structural delta vs the 6.3 TB/s m13 copy reference:
// barrier-free exact-fill grid-stride persistence. 2048 blocks x 256 = 8
// blocks/CU EXACTLY (100% theoretical occupancy); each thread walks 6 items
// at stride 2^19. Stride choice makes (h, w0) per-thread CONSTANT across
// iterations (2^19/2^8 = 2048 === 0 mod 512), so all edge masks and clamped
// offsets are loop-invariant; only bc advances (+4/iter, covers 0..23
// exactly). Waves re-issue memory continuously for 6 items instead of
// paying fill/drain/teardown per item. No LDS, no barriers, no asm.
// Body identical to the proven R0 kernel.

#define DIA 2

__global__ __launch_bounds__(256) void fused_kernel(
    const float* __restrict__ x, const float* __restrict__ y,
    const float* __restrict__ w1v, const float* __restrict__ b1v,
    const float* __restrict__ w2v, const float* __restrict__ b2v,
    float* __restrict__ out)
{
    constexpr int C = 3, H = 512, W = 512, W2 = 1024;

    int gid = blockIdx.x * 256 + (int)threadIdx.x;           // 0..524287
    int wp  = gid & (W / 2 - 1);                             // 0..255, lane-contiguous
    int h   = __builtin_amdgcn_readfirstlane((gid >> 8) & (H - 1));
    int bc0 = __builtin_amdgcn_readfirstlane(gid >> 17);     // 0..3
    int w0  = wp * 2;                                        // even, 0..510

    // ---- loop-invariant geometry (constant because stride keeps h, w0 fixed)
    const bool ok0 = (h >= DIA), ok2 = (h < H - DIA);
    const bool lok = (w0 > 0), rok = (w0 + 2 < W);
    const float m0 = ok0 ? 1.f : 0.f;
    const float m2 = ok2 ? 1.f : 0.f;
    const float mL = lok ? 1.f : 0.f;
    const float mR = rok ? 1.f : 0.f;
    const int wl = lok ? (w0 - 2) : w0;    // clamped, in-bounds, 8B-aligned
    const int wr = rok ? (w0 + 2) : w0;
    const int d0 = ok0 ? -DIA * W : 0;     // clamped row offsets
    const int d2 = ok2 ?  DIA * W : 0;

    for (int it = 0; it < 6; ++it) {
        const int bc = bc0 + it * 4;       // 0..23, wave-uniform
        const int c  = bc % C;

        const float s_w1 = w1v[c], s_b1 = b1v[c];   // wave-uniform -> scalar loads
        const float s_w2 = w2v[c], s_b2 = b2v[c];

        const float* xrow = x + ((size_t)bc * H + (size_t)h) * W;
        const float* r0 = xrow + d0;
        const float* r2 = xrow + d2;

        // ---- loads (same proven R0 pattern) ----
        float2 L0 = *(const float2*)(r0 + wl);
        float2 M0 = *(const float2*)(r0 + w0);
        float2 R0 = *(const float2*)(r0 + wr);
        float2 L1 = *(const float2*)(xrow + wl);
        float2 M1 = *(const float2*)(xrow + w0);
        float2 R1 = *(const float2*)(xrow + wr);
        float2 L2 = *(const float2*)(r2 + wl);
        float2 M2 = *(const float2*)(r2 + w0);
        float2 R2 = *(const float2*)(r2 + wr);

        size_t obase = (((size_t)bc * (2 * H) + (size_t)(2 * h)) * W2) + (size_t)(2 * w0);
        float4 ya = *(const float4*)(y + obase);
        float4 yb = *(const float4*)(y + obase + W2);

        // ---- compute ----
        auto act = [&](float v) { return fmaxf(fmaf(v, s_w1, s_b1), 0.f); };

        float xo0 = act(M1.x);
        float xo1 = act(M1.y);

        float sum0 = mL * act(L1.x) + xo0 + mR * act(R1.x);
        float sum1 = mL * act(L1.y) + xo1 + mR * act(R1.y);
        sum0 += m0 * (mL * act(L0.x) + act(M0.x) + mR * act(R0.x));
        sum1 += m0 * (mL * act(L0.y) + act(M0.y) + mR * act(R0.y));
        sum0 += m2 * (mL * act(L2.x) + act(M2.x) + mR * act(R2.x));
        sum1 += m2 * (mL * act(L2.y) + act(M2.y) + mR * act(R2.y));

        float z0 = fmaf(sum0, s_w2, s_b2);
        float z1 = fmaf(sum1, s_w2, s_b2);
        float o0 = xo0 / (1.f + __expf(-z0));
        float o1 = xo1 / (1.f + __expf(-z1));

        // ---- 2x nearest upsample + add y (lane-contiguous float4) ----
        *(float4*)(out + obase)      = make_float4(ya.x + o0, ya.y + o0, ya.z + o1, ya.w + o1);
        *(float4*)(out + obase + W2) = make_float4(yb.x + o0, yb.y + o0, yb.z + o1, yb.w + o1);
    }
}

extern "C" void kernel_launch(void* const* d_in, const int* in_sizes, int n_in,
                              void* d_out, int out_size, void* d_ws, size_t ws_size,
                              hipStream_t stream) {
    const float* x  = (const float*)d_in[0];
    const float* y  = (const float*)d_in[1];
    const float* w1 = (const float*)d_in[2];
    const float* b1 = (const float*)d_in[3];
    const float* w2 = (const float*)d_in[4];
    const float* b2 = (const float*)d_in[5];
    float* out = (float*)d_out;

    // 2048 blocks x 256 threads = 8 blocks/CU exactly; 6 items per thread
    // (2048*256*6 == 8*3*512*256 work items, exact cover, no residue).
    int grid = 2048, block = 256;
    fused_kernel<<<grid, block, 0, stream>>>(x, y, w1, b1, w2, b2, out);
}